// Round 6
// baseline (284.922 us; speedup 1.0000x reference)
//
#include <hip/hip_runtime.h>

#define BB 32
#define TT 2000
#define NG 500          // float4 groups per alphas row
#define HH 512
#define LL 256
#define THRESH 0.95f

#define CHUNK 512       // scan steps staged per chunk
#define NCH 4           // 4*512 = 2048 >= 2000 (tail zero-padded; zeros never fire)
#define BPB 8           // batches per scan block (4 blocks total)
#define SPAD 9          // LDS batch stride (8+1, kills stage-write conflicts)
#define NWIN 16         // 32-step mask windows per chunk

// d_ws layout:
//   int2  rec[BB*LL]  : per-fire {t, bits(dist)}  (rem recomputed as a*sc-dist)
//   int   nfires[BB]
//   float scale[BB]

// ---- per-batch rescale factor (bit-identical to R5's phase 1) ----
__global__ __launch_bounds__(256) void cif_scale_kernel(
    const float* __restrict__ alphas, const int* __restrict__ tlen,
    float* __restrict__ scale_g)
{
    const int b = blockIdx.x;
    const int tid = threadIdx.x;
    __shared__ double red[256];
    const float4* a4 = (const float4*)(alphas + b * TT);
    double s = 0.0;
    for (int g = tid; g < NG; g += 256) {
        float4 v = a4[g];
        s += (double)v.x + (double)v.y + (double)v.z + (double)v.w;
    }
    red[tid] = s;
    __syncthreads();
    for (int off = 128; off > 0; off >>= 1) {
        if (tid < off) red[tid] += red[tid + off];
        __syncthreads();
    }
    if (tid == 0)
        scale_g[b] = (float)tlen[b] / (float)red[0];   // f32 divide, as reference
}

// ---- lockstep scan: lane = batch. 8 batches share one wave's issue slots. ----
__global__ __launch_bounds__(256) void cif_scan_kernel(
    const float* __restrict__ alphas, const float* __restrict__ scale_g,
    int2* __restrict__ rec, int* __restrict__ nfires)
{
    const int b0 = blockIdx.x * BPB;
    const int tid = threadIdx.x;
    __shared__ float saT[CHUNK * SPAD];      // scaled alphas, [t][b] transposed
    __shared__ float ipT[CHUNK * SPAD];      // post-step integ, [t][b]
    __shared__ unsigned smask[NWIN * BPB];   // fire masks
    __shared__ float scs[BPB];

    if (tid < BPB) scs[tid] = scale_g[b0 + tid];
    __syncthreads();

    // Persistent per-lane scan state (meaningful on lanes 0..7 of wave 0).
    float integ = 0.0f;
    float carry_in = 0.0f;   // integ entering current chunk
    int tok = 0;

    for (int c = 0; c < NCH; ++c) {
        // ---- stage: thread group (tid>>5) stages batch b0+(tid>>5);
        // sa = fl(a*sc), the exact mul the gather recomputes. ----
        {
            const int bl = tid >> 5;
            const int lane = tid & 31;
            const float sc = scs[bl];
            const float* arow = alphas + (size_t)(b0 + bl) * TT + c * CHUNK;
            #pragma unroll
            for (int j = 0; j < CHUNK / 32; ++j) {
                const int t = lane + j * 32;
                const int gt = c * CHUNK + t;
                const float a = (gt < TT) ? arow[t] : 0.0f;
                saT[t * SPAD + bl] = a * sc;
            }
        }
        __syncthreads();

        // ---- serial lockstep scan (branchless; masks in VGPR, b32 flush/32). ----
        if (tid < BPB) {
            carry_in = integ;
            for (int w = 0; w < NWIN; ++w) {
                unsigned mask = 0;
                #pragma unroll
                for (int j = 0; j < 32; ++j) {
                    const int t = w * 32 + j;
                    const float a = saT[t * SPAD + tid];
                    float ii = integ + a;              // integrate += alpha
                    const bool fire = (ii >= THRESH);
                    const float iim1 = ii - 1.0f;      // off-chain vs cmp
                    ii = fire ? iim1 : ii;             // cndmask
                    mask |= fire ? (1u << j) : 0u;
                    ipT[t * SPAD + tid] = ii;
                    integ = ii;
                }
                smask[w * BPB + tid] = mask;
            }
        }
        __syncthreads();

        // ---- emit fires (lanes 0..7, parallel over batches, off serial path) ----
        if (tid < BPB) {
            const int b = b0 + tid;
            for (int w = 0; w < NWIN; ++w) {
                unsigned m = smask[w * BPB + tid];
                while (m) {
                    const int j = __ffs(m) - 1;
                    m &= m - 1;
                    const int t = w * 32 + j;
                    if (tok < LL) {
                        const float prev = (t == 0) ? carry_in
                                                    : ipT[(t - 1) * SPAD + tid];
                        int2 r;
                        r.x = c * CHUNK + t;
                        r.y = __float_as_int(1.0f - prev);   // dist_completion
                        rec[b * LL + tok] = r;
                    }
                    ++tok;
                }
            }
        }
        __syncthreads();    // protect saT/ipT before next chunk's staging
    }
    if (tid < BPB) nfires[b0 + tid] = (tok < LL) ? tok : LL;
}

// ---- gather: unchanged from R5 (validated) ----
__global__ __launch_bounds__(128) void cif_gather_kernel(
    const float* __restrict__ hidden, const float* __restrict__ alphas,
    const float* __restrict__ scale_g, const int2* __restrict__ rec,
    const int* __restrict__ nfires, float* __restrict__ out)
{
    const int l = blockIdx.x;       // token index
    const int b = blockIdx.y;       // batch
    const int tid = threadIdx.x;    // 128 threads x float4 = 512 = HH

    float4 acc = make_float4(0.f, 0.f, 0.f, 0.f);
    const int F = nfires[b];
    if (l < F) {
        const int2 re = rec[b * LL + l];
        const int e = re.x;                        // fire step of this token
        const float dist = __int_as_float(re.y);   // weight of frame e
        const float sc = scale_g[b];
        const float* hb = hidden + (size_t)b * TT * HH + (size_t)tid * 4;
        const float* ab = alphas + b * TT;
        int t0 = 0;
        if (l > 0) {
            const int2 rp = rec[b * LL + l - 1];
            const int sp = rp.x;
            const float dp = __int_as_float(rp.y);
            const float rem = ab[sp] * sc - dp;    // a - cur, bit-exact
            const float4 hv = *(const float4*)(hb + (size_t)sp * HH);
            acc.x = rem * hv.x; acc.y = rem * hv.y;
            acc.z = rem * hv.z; acc.w = rem * hv.w;
            t0 = sp + 1;
        }
        // Ascending t (reference order), depth-2 load pipeline; interior
        // weight = alphas[t]*sc (bit-identical to scan), dist at t==e.
        int t = t0;
        float w0 = (t < e) ? ab[t] * sc : dist;
        float4 h0 = *(const float4*)(hb + (size_t)t * HH);
        if (t < e) {
            float w1 = (t + 1 < e) ? ab[t + 1] * sc : dist;
            float4 h1 = *(const float4*)(hb + (size_t)(t + 1) * HH);
            while (t + 2 <= e) {
                const float w2 = (t + 2 < e) ? ab[t + 2] * sc : dist;
                const float4 h2 = *(const float4*)(hb + (size_t)(t + 2) * HH);
                acc.x += w0 * h0.x; acc.y += w0 * h0.y;
                acc.z += w0 * h0.z; acc.w += w0 * h0.w;
                w0 = w1; h0 = h1; w1 = w2; h1 = h2; ++t;
            }
            acc.x += w0 * h0.x; acc.y += w0 * h0.y;
            acc.z += w0 * h0.z; acc.w += w0 * h0.w;
            w0 = w1; h0 = h1;
        }
        acc.x += w0 * h0.x; acc.y += w0 * h0.y;
        acc.z += w0 * h0.z; acc.w += w0 * h0.w;
    }
    *(float4*)(out + ((size_t)b * LL + l) * HH + (size_t)tid * 4) = acc;
}

extern "C" void kernel_launch(void* const* d_in, const int* in_sizes, int n_in,
                              void* d_out, int out_size, void* d_ws, size_t ws_size,
                              hipStream_t stream) {
    const float* hidden = (const float*)d_in[0];   // [B,T,H] f32
    const float* alphas = (const float*)d_in[1];   // [B,T]   f32
    const int*   tlen   = (const int*)d_in[2];     // [B]     i32
    float* out = (float*)d_out;                    // [B,L,H] f32

    int2*  rec     = (int2*)d_ws;
    int*   nfires  = (int*)(rec + BB * LL);
    float* scale_g = (float*)(nfires + BB);

    cif_scale_kernel<<<BB, 256, 0, stream>>>(alphas, tlen, scale_g);
    cif_scan_kernel<<<4, 256, 0, stream>>>(alphas, scale_g, rec, nfires);
    cif_gather_kernel<<<dim3(LL, BB), 128, 0, stream>>>(hidden, alphas, scale_g,
                                                        rec, nfires, out);
}